// Round 1
// baseline (25099.760 us; speedup 1.0000x reference)
//
#include <hip/hip_runtime.h>
#include <math.h>

// Problem constants (fixed by the reference)
constexpr int B    = 512;
constexpr int T    = 64;
constexpr int H    = 512;
constexpr int V    = 780;
constexpr int N_AT = 40;
constexpr int KC   = 4;
constexpr int NB   = 8;     // MAX_NB
constexpr int BT   = B * T;         // 32768
constexpr int NMSG = BT + 1;        // 32769

// ---------------------------------------------------------------------------
// Generic 32x32-tile fp32 GEMM over K=H (or K=2H via two A operands).
// C[m,n] = epilogue( sum_k A[m,k] * W[k,n] + bias[n] )
// modes:
//   0: plain            C = A1@W + bias
//   1: sigmoid cat2     C = sigmoid(A1@W[0:H] + A2@W[H:2H] + bias)
//   2: tanh cat2 + GRU  preh = tanh(...); C = (1-Ez)*Esh + Ez*preh  (C has ldC)
//   3: relu cat2        C = relu(A1@W[0:H] + A2@W[H:2H] + bias)
//   4: gather plain     A rows = table[nei_h_idx[b,gt,n]] (m = b*NB+n), no bias
// ---------------------------------------------------------------------------
__global__ __launch_bounds__(256)
void gemm_k(const float* __restrict__ A1, const float* __restrict__ A2,
            const float* __restrict__ W, const float* __restrict__ bias,
            float* __restrict__ C, int ldC,
            const int* __restrict__ gidx, int gt,
            const float* __restrict__ table,
            const float* __restrict__ Ez, const float* __restrict__ Esh,
            int mode)
{
    __shared__ float As[32][33];
    __shared__ float Ws[32][33];
    const int tid  = threadIdx.x;
    const int tr   = tid >> 4;        // 0..15
    const int tc   = tid & 15;        // 0..15
    const int row0 = blockIdx.x * 32;
    const int col0 = blockIdx.y * 32;

    float a00 = 0.f, a01 = 0.f, a10 = 0.f, a11 = 0.f;
    const int nseg = (mode == 1 || mode == 2 || mode == 3) ? 2 : 1;

    for (int seg = 0; seg < nseg; ++seg) {
        const float* A    = (seg == 0) ? A1 : A2;
        const float* Wseg = W + (size_t)seg * H * H;
        for (int k0 = 0; k0 < H; k0 += 32) {
#pragma unroll
            for (int i = 0; i < 4; ++i) {
                const int idx = tid + i * 256;
                const int r  = idx >> 5;   // 0..31
                const int cc = idx & 31;   // 0..31
                const float* Arow;
                if (mode == 4) {
                    const int gr = row0 + r;
                    const int gi = gidx[((gr >> 3) * T + gt) * NB + (gr & 7)];
                    Arow = table + (size_t)gi * H;
                } else {
                    Arow = A + (size_t)(row0 + r) * H;
                }
                As[r][cc] = Arow[k0 + cc];
                Ws[r][cc] = Wseg[(size_t)(k0 + r) * H + (col0 + cc)];
            }
            __syncthreads();
#pragma unroll
            for (int kk = 0; kk < 32; ++kk) {
                const float x0 = As[tr][kk];
                const float x1 = As[tr + 16][kk];
                const float w0 = Ws[kk][tc];
                const float w1 = Ws[kk][tc + 16];
                a00 += x0 * w0; a01 += x0 * w1;
                a10 += x1 * w0; a11 += x1 * w1;
            }
            __syncthreads();
        }
    }

    const float b0 = bias ? bias[col0 + tc]      : 0.f;
    const float b1 = bias ? bias[col0 + tc + 16] : 0.f;

    auto epi = [&](float acc, int r, int c, float bv) {
        float val = acc + bv;
        if (mode == 1) {
            val = 1.f / (1.f + expf(-val));
        } else if (mode == 2) {
            const float ph = tanhf(val);
            const float zz = Ez[(size_t)r * H + c];
            const float sh = Esh[(size_t)r * H + c];
            val = (1.f - zz) * sh + zz * ph;
        } else if (mode == 3) {
            val = fmaxf(val, 0.f);
        }
        C[(size_t)r * ldC + c] = val;
    };
    epi(a00, row0 + tr,      col0 + tc,      b0);
    epi(a01, row0 + tr,      col0 + tc + 16, b1);
    epi(a10, row0 + tr + 16, col0 + tc,      b0);
    epi(a11, row0 + tr + 16, col0 + tc + 16, b1);
}

// ---------------------------------------------------------------------------
// Per-step gathers: x_t (clique sum), sum_h (nei_h gather-sum), o (nei_o sum)
// ---------------------------------------------------------------------------
__global__ __launch_bounds__(256)
void pre_kernel(const float* __restrict__ node_rep, const int* __restrict__ clique_idx,
                const int* __restrict__ nei_h, const int* __restrict__ nei_o,
                const float* __restrict__ table,
                float* __restrict__ xt, float* __restrict__ sumh, float* __restrict__ ot,
                int t)
{
    const int i = blockIdx.x * 256 + threadIdx.x;   // B*H threads
    const int b = i >> 9, h = i & 511;
    const int* ci = clique_idx + ((size_t)b * T + t) * KC;
    float x = 0.f;
#pragma unroll
    for (int k = 0; k < KC; ++k)
        x += node_rep[((size_t)b * N_AT + ci[k]) * H + h];
    xt[i] = x;
    const int* hi = nei_h + ((size_t)b * T + t) * NB;
    const int* oi = nei_o + ((size_t)b * T + t) * NB;
    float sh = 0.f, so = 0.f;
#pragma unroll
    for (int n = 0; n < NB; ++n) {
        sh += table[(size_t)hi[n] * H + h];
        so += table[(size_t)oi[n] * H + h];
    }
    sumh[i] = sh;
    ot[i]   = so;
}

// sum_g[b,h] = sum_n sigmoid(xr[b,h] + hU[b*NB+n,h]) * table[nei_h[b,t,n]][h]
__global__ __launch_bounds__(256)
void rsum_kernel(const float* __restrict__ xr, const float* __restrict__ hU,
                 const float* __restrict__ table, const int* __restrict__ nei_h,
                 float* __restrict__ sumg, int t)
{
    const int i = blockIdx.x * 256 + threadIdx.x;
    const int b = i >> 9, h = i & 511;
    const int* hi = nei_h + ((size_t)b * T + t) * NB;
    const float xrv = xr[i];
    float s = 0.f;
#pragma unroll
    for (int n = 0; n < NB; ++n) {
        const float hu = hU[((size_t)b * NB + n) * H + h];
        const float r  = 1.f / (1.f + expf(-(xrv + hu)));
        s += r * table[(size_t)hi[n] * H + h];
    }
    sumg[i] = s;
}

// Root features: root_x and root_o
__global__ __launch_bounds__(256)
void rootpre_kernel(const float* __restrict__ node_rep, const int* __restrict__ rci,
                    const int* __restrict__ rni, const float* __restrict__ table,
                    float* __restrict__ xt, float* __restrict__ ot)
{
    const int i = blockIdx.x * 256 + threadIdx.x;
    const int b = i >> 9, h = i & 511;
    float x = 0.f;
#pragma unroll
    for (int k = 0; k < KC; ++k)
        x += node_rep[((size_t)b * N_AT + rci[b * KC + k]) * H + h];
    float so = 0.f;
#pragma unroll
    for (int n = 0; n < NB; ++n)
        so += table[(size_t)rni[b * NB + n] * H + h];
    xt[i] = x;
    ot[i] = so;
}

// score[b] = s1[b,:] . U_s_w + U_s_b  (one wave per row)
__global__ __launch_bounds__(64)
void stopdot_kernel(const float* __restrict__ s1, const float* __restrict__ Usw,
                    const float* __restrict__ Usb,
                    float* __restrict__ out, int outStride, int outBase)
{
    const int b = blockIdx.x;
    const int lane = threadIdx.x;
    const float* row = s1 + (size_t)b * H;
    float s = 0.f;
    for (int h = lane; h < H; h += 64) s += row[h] * Usw[h];
#pragma unroll
    for (int off = 32; off; off >>= 1) s += __shfl_down(s, off);
    if (lane == 0) out[outBase + b * outStride] = s + Usb[0];
}

// BCE-with-logits sum + accuracy over BT+B rows
__global__ __launch_bounds__(256)
void stoploss_kernel(const float* __restrict__ scores, const int* __restrict__ direction,
                     float* __restrict__ accum)
{
    const int i = blockIdx.x * 256 + threadIdx.x;
    float loss = 0.f, acc = 0.f;
    if (i < BT + B) {
        const float s   = scores[i];
        const float tgt = (i < BT) ? (float)direction[i] : 0.f;
        loss = fmaxf(s, 0.f) - s * tgt + log1pf(expf(-fabsf(s)));
        const float p = (s >= 0.f) ? 1.f : 0.f;
        acc = (p == tgt) ? 1.f : 0.f;
    }
#pragma unroll
    for (int off = 32; off; off >>= 1) {
        loss += __shfl_down(loss, off);
        acc  += __shfl_down(acc, off);
    }
    if ((threadIdx.x & 63) == 0) {
        atomicAdd(&accum[3], loss);
        atomicAdd(&accum[4], acc);
    }
}

// ---------------------------------------------------------------------------
// Fused pred head: per block, 8 rows:
//   h = table[1+row]  ->  s1 = relu(h@W_w + W_b)  ->  scores = s1@W_o_w + W_o_b
//   -> log-softmax CE at target, argmax, masked accumulate
// ---------------------------------------------------------------------------
constexpr int PH_ROWS = 8;
__global__ __launch_bounds__(256)
void predhead_kernel(const float* __restrict__ table,
                     const float* __restrict__ Ww, const float* __restrict__ Wb,
                     const float* __restrict__ Wo, const float* __restrict__ Wob,
                     const int* __restrict__ direction, const int* __restrict__ ptgt,
                     float* __restrict__ accum)
{
    __shared__ float hs[PH_ROWS][520];    // +8 pad: rows land in distinct banks
    __shared__ float s1s[PH_ROWS][520];
    const int row0 = blockIdx.x * PH_ROWS;
    const int tid  = threadIdx.x;

    // load 8 h rows (table rows 1..BT are new_h_all)
    for (int i = tid; i < PH_ROWS * H; i += 256) {
        const int r = i >> 9, c = i & 511;
        hs[r][c] = table[(size_t)(row0 + r + 1) * H + c];
    }
    __syncthreads();

    const int r  = tid >> 5;   // 0..7 (row)
    const int tx = tid & 31;   // 0..31 (col lane)

    // GEMM1: s1 = relu(h @ Ww + Wb); each thread: 16 columns
    for (int j = 0; j < 16; ++j) {
        const int c = tx + j * 32;
        float acc = Wb[c];
        for (int k = 0; k < H; ++k)
            acc += hs[r][k] * Ww[(size_t)k * H + c];
        s1s[r][c] = fmaxf(acc, 0.f);
    }
    __syncthreads();

    // GEMM2 + online logsumexp + argmax + target pick
    const int row = row0 + r;
    const int tgt = ptgt[row];
    float m = -1e30f, ssum = 0.f, stgt = 0.f;
    float bestv = -1e30f; int bestj = 0;
    for (int v = tx; v < V; v += 32) {
        float sc = Wob[v];
        const float* wcol = Wo + v;
        for (int k = 0; k < H; ++k)
            sc += s1s[r][k] * wcol[(size_t)k * V];
        if (sc > m) { ssum = ssum * expf(m - sc) + 1.f; m = sc; }
        else        { ssum += expf(sc - m); }
        if (sc > bestv) { bestv = sc; bestj = v; }
        if (v == tgt) stgt = sc;
    }
    // butterfly reduce across the 32 col-lanes
#pragma unroll
    for (int off = 1; off < 32; off <<= 1) {
        const float om = __shfl_xor(m, off);
        const float os = __shfl_xor(ssum, off);
        const float nm = fmaxf(m, om);
        ssum = ssum * expf(m - nm) + os * expf(om - nm);
        m = nm;
        const float obv = __shfl_xor(bestv, off);
        const int   obj = __shfl_xor(bestj, off);
        if (obv > bestv || (obv == bestv && obj < bestj)) { bestv = obv; bestj = obj; }
        stgt += __shfl_xor(stgt, off);
    }
    if (tx == 0) {
        const float lse  = m + logf(ssum);
        const float ce   = lse - stgt;
        const float mask = (direction[row] == 1) ? 1.f : 0.f;
        const float corr = (bestj == tgt) ? 1.f : 0.f;
        atomicAdd(&accum[0], ce * mask);
        atomicAdd(&accum[1], mask);
        atomicAdd(&accum[2], corr * mask);
    }
}

__global__ void finalize_kernel(const float* __restrict__ accum, float* __restrict__ out)
{
    if (threadIdx.x == 0) {
        out[0] = accum[0] / (float)B;           // pred_loss
        out[1] = accum[3] / (float)B;           // stop_loss
        out[2] = accum[2] / accum[1];           // pred_acc
        out[3] = accum[4] / (float)(BT + B);    // stop_acc
    }
}

// ---------------------------------------------------------------------------
extern "C" void kernel_launch(void* const* d_in, const int* in_sizes, int n_in,
                              void* d_out, int out_size, void* d_ws, size_t ws_size,
                              hipStream_t stream)
{
    (void)in_sizes; (void)n_in; (void)out_size; (void)ws_size;

    const float* node_rep        = (const float*)d_in[0];
    const int*   clique_idx      = (const int*)d_in[1];
    const int*   root_clique_idx = (const int*)d_in[2];
    const int*   nei_h_idx       = (const int*)d_in[3];
    const int*   nei_o_idx       = (const int*)d_in[4];
    const int*   root_nei_idx    = (const int*)d_in[5];
    const int*   direction       = (const int*)d_in[6];
    const int*   pred_target     = (const int*)d_in[7];
    const float* W_z_w = (const float*)d_in[8];
    const float* W_z_b = (const float*)d_in[9];
    const float* W_r_w = (const float*)d_in[10];
    const float* W_r_b = (const float*)d_in[11];
    const float* U_r_w = (const float*)d_in[12];
    const float* W_h_w = (const float*)d_in[13];
    const float* W_h_b = (const float*)d_in[14];
    const float* W_w   = (const float*)d_in[15];
    const float* W_b   = (const float*)d_in[16];
    const float* U_w   = (const float*)d_in[17];
    const float* U_b   = (const float*)d_in[18];
    const float* W_o_w = (const float*)d_in[19];
    const float* W_o_b = (const float*)d_in[20];
    const float* U_s_w = (const float*)d_in[21];
    const float* U_s_b = (const float*)d_in[22];

    float* ws = (float*)d_ws;
    size_t off = 0;
    float* table  = ws + off; off += (size_t)NMSG * H;   // 16.78M floats
    float* xt     = ws + off; off += (size_t)B * H;
    float* sumh   = ws + off; off += (size_t)B * H;
    float* ot     = ws + off; off += (size_t)B * H;
    float* zbuf   = ws + off; off += (size_t)B * H;
    float* xr     = ws + off; off += (size_t)B * H;
    float* sumg   = ws + off; off += (size_t)B * H;
    float* s1stop = ws + off; off += (size_t)B * H;
    float* hU     = ws + off; off += (size_t)B * NB * H; // 2.10M floats
    float* stop_scores = ws + off; off += BT + B;
    float* accum  = ws + off; off += 8;

    // zero the message table (slot 0 + future-message reads must be 0) and accumulators
    hipMemsetAsync(table, 0, (size_t)NMSG * H * sizeof(float), stream);
    hipMemsetAsync(accum, 0, 8 * sizeof(float), stream);

    const int BH_blocks = (B * H) / 256;   // 1024
    const dim3 gB(B / 32, H / 32);         // (16,16)   M=512 GEMMs
    const dim3 gU(B * NB / 32, H / 32);    // (128,16)  M=4096 gathered GEMM

    for (int t = 0; t < T; ++t) {
        pre_kernel<<<BH_blocks, 256, 0, stream>>>(node_rep, clique_idx, nei_h_idx,
                                                  nei_o_idx, table, xt, sumh, ot, t);
        // z = sigmoid([x, sum_h] @ W_z + b_z)
        gemm_k<<<gB, 256, 0, stream>>>(xt, sumh, W_z_w, W_z_b, zbuf, H,
                                       nullptr, 0, nullptr, nullptr, nullptr, 1);
        // xr = x @ W_r + b_r
        gemm_k<<<gB, 256, 0, stream>>>(xt, nullptr, W_r_w, W_r_b, xr, H,
                                       nullptr, 0, nullptr, nullptr, nullptr, 0);
        // hU = gather(table, nei_h[:,t,:]) @ U_r
        gemm_k<<<gU, 256, 0, stream>>>(nullptr, nullptr, U_r_w, nullptr, hU, H,
                                       nei_h_idx, t, table, nullptr, nullptr, 4);
        // sum_g = sum_n sigmoid(xr + hU_n) * h_nei_n
        rsum_kernel<<<BH_blocks, 256, 0, stream>>>(xr, hU, table, nei_h_idx, sumg, t);
        // new_h = (1-z)*sum_h + z*tanh([x,sum_g]@W_h + b_h)  -> table[b*T+t+1]
        gemm_k<<<gB, 256, 0, stream>>>(xt, sumg, W_h_w, W_h_b,
                                       table + (size_t)(t + 1) * H, T * H,
                                       nullptr, 0, nullptr, zbuf, sumh, 2);
        // stop head this step: s1 = relu([x, o] @ U_w + U_b)
        gemm_k<<<gB, 256, 0, stream>>>(xt, ot, U_w, U_b, s1stop, H,
                                       nullptr, 0, nullptr, nullptr, nullptr, 3);
        stopdot_kernel<<<B, 64, 0, stream>>>(s1stop, U_s_w, U_s_b, stop_scores, T, t);
    }

    // root stop row: [root_x, root_o]
    rootpre_kernel<<<BH_blocks, 256, 0, stream>>>(node_rep, root_clique_idx,
                                                  root_nei_idx, table, xt, ot);
    gemm_k<<<gB, 256, 0, stream>>>(xt, ot, U_w, U_b, s1stop, H,
                                   nullptr, 0, nullptr, nullptr, nullptr, 3);
    stopdot_kernel<<<B, 64, 0, stream>>>(s1stop, U_s_w, U_s_b, stop_scores, 1, BT);

    stoploss_kernel<<<(BT + B + 255) / 256, 256, 0, stream>>>(stop_scores, direction, accum);

    predhead_kernel<<<BT / PH_ROWS, 256, 0, stream>>>(table, W_w, W_b, W_o_w, W_o_b,
                                                      direction, pred_target, accum);

    finalize_kernel<<<1, 64, 0, stream>>>(accum, (float*)d_out);
}

// Round 3
// 13482.463 us; speedup vs baseline: 1.8617x; 1.8617x over previous
//
#include <hip/hip_runtime.h>
#include <math.h>

// Problem constants (fixed by the reference)
constexpr int B    = 512;
constexpr int T    = 64;
constexpr int H    = 512;
constexpr int V    = 780;
constexpr int N_AT = 40;
constexpr int KC   = 4;
constexpr int NB   = 8;
constexpr int BT   = B * T;      // 32768
constexpr int NMSG = BT + 1;     // 32769

// ---------------------------------------------------------------------------
// 64x64-tile fp32 GEMM core.  256 threads, 4x4 acc per thread, KTILE=32.
// A staged TRANSPOSED in LDS (As[k][m]) so fragments are ds_read_b128.
// ASRC: 0 = plain ptr (A1 seg0 / A2 seg1, row stride lda)
//       1 = gather rows from table via nei_h_idx[b][gt][n]  (row m = b*NB+n)
//       2 = clique-gather: A[m][k] = sum_j node_rep[m>>6][cliq[m*4+j]][k]
//       3 = stop-A: seg0 clique-gather (or root-clique for m>=BT),
//                   seg1 o_all row m   (or root-nei table sum for m>=BT)
// EPI:  0 none(+bias) | 1 sigmoid | 2 GRU blend | 3 relu | 4 relu*Usw partial
// ---------------------------------------------------------------------------
template<int ASRC, int NSEG, int EPI>
__device__ __forceinline__ void gemm_core(
    float* smem, int bx, int by,
    const float* __restrict__ A1, const float* __restrict__ A2, int lda,
    const float* __restrict__ W, const float* __restrict__ bias,
    float* __restrict__ C, int ldc,
    const int* __restrict__ gidx, int gt, const float* __restrict__ table,
    const float* __restrict__ node_rep, const int* __restrict__ cliq,
    const float* __restrict__ o_all,
    const int* __restrict__ rci, const int* __restrict__ rni,
    const float* __restrict__ Ez, const float* __restrict__ Esh,
    const float* __restrict__ Usw, float* __restrict__ partial)
{
    float* As = smem;            // [32][68] transposed: As[k][m]
    float* Ws = smem + 32 * 68;  // [32][68]: Ws[k][n]
    const int tid  = threadIdx.x;
    const int row0 = bx * 64;
    const int col0 = by * 64;
    const int tm   = tid >> 4;   // 0..15 -> rows tm*4..+3
    const int tn   = tid & 15;   // 0..15 -> cols tn*4..+3

    float acc[4][4] = {};

    // staging index decompositions (A-tile: 64 m x 32 k; W-tile: 32 k x 64 n)
    const int ar0 = tid >> 5;    // A m-row seed, 0..7  (+8 per it)
    const int ac  = tid & 31;    // A k-col, 0..31
    const int wk0 = tid >> 6;    // W k-row seed, 0..3  (+4 per it)
    const int wc  = tid & 63;    // W n-col, 0..63

    for (int seg = 0; seg < NSEG; ++seg) {
        const float* Aseg = seg ? A2 : A1;
        const float* Wseg = W + (size_t)seg * H * H;
        for (int k0 = 0; k0 < H; k0 += 32) {
#pragma unroll
            for (int it = 0; it < 8; ++it) {
                const int r    = ar0 + it * 8;     // 0..63
                const int grow = row0 + r;
                float v;
                if (ASRC == 0) {
                    v = Aseg[(size_t)grow * lda + k0 + ac];
                } else if (ASRC == 1) {
                    const int gi = gidx[((grow >> 3) * T + gt) * NB + (grow & 7)];
                    v = table[(size_t)gi * H + k0 + ac];
                } else if (ASRC == 2) {
                    const int* ci = cliq + (size_t)grow * KC;
                    const int  b  = grow >> 6;      // row m = b*T + t, T = 64
                    v = 0.f;
#pragma unroll
                    for (int j = 0; j < KC; ++j)
                        v += node_rep[((size_t)b * N_AT + ci[j]) * H + k0 + ac];
                } else {  // ASRC == 3 (stop head A)
                    if (grow < BT) {
                        if (seg == 0) {
                            const int* ci = cliq + (size_t)grow * KC;
                            const int  b  = grow >> 6;
                            v = 0.f;
#pragma unroll
                            for (int j = 0; j < KC; ++j)
                                v += node_rep[((size_t)b * N_AT + ci[j]) * H + k0 + ac];
                        } else {
                            v = o_all[(size_t)grow * H + k0 + ac];
                        }
                    } else {
                        const int b = grow - BT;
                        v = 0.f;
                        if (seg == 0) {
#pragma unroll
                            for (int j = 0; j < KC; ++j)
                                v += node_rep[((size_t)b * N_AT + rci[b * KC + j]) * H + k0 + ac];
                        } else {
#pragma unroll
                            for (int n = 0; n < NB; ++n)
                                v += table[(size_t)rni[b * NB + n] * H + k0 + ac];
                        }
                    }
                }
                As[(size_t)ac * 68 + r] = v;                       // transposed
                const int kk = wk0 + it * 4;       // 0..31
                Ws[(size_t)kk * 68 + wc] = Wseg[(size_t)(k0 + kk) * H + col0 + wc];
            }
            __syncthreads();
#pragma unroll
            for (int kk = 0; kk < 32; ++kk) {
                float a[4], w[4];
                *(float4*)a = *(const float4*)&As[kk * 68 + tm * 4];
                *(float4*)w = *(const float4*)&Ws[kk * 68 + tn * 4];
#pragma unroll
                for (int i = 0; i < 4; ++i)
#pragma unroll
                    for (int j = 0; j < 4; ++j)
                        acc[i][j] = fmaf(a[i], w[j], acc[i][j]);
            }
            __syncthreads();
        }
    }

    if (EPI == 4) {
        // relu(acc + Ub) dotted with Usw over this 64-col block -> partial[row][by]
        float* sred = smem + 2 * 32 * 68;   // [64][17]
#pragma unroll
        for (int i = 0; i < 4; ++i) {
            float s = 0.f;
#pragma unroll
            for (int j = 0; j < 4; ++j) {
                const int ccol = col0 + tn * 4 + j;
                float val = acc[i][j] + bias[ccol];
                val = fmaxf(val, 0.f);
                s += val * Usw[ccol];
            }
            sred[(size_t)(tm * 4 + i) * 17 + tn] = s;
        }
        __syncthreads();
        if (tid < 64) {
            float s = 0.f;
#pragma unroll
            for (int t2 = 0; t2 < 16; ++t2) s += sred[(size_t)tid * 17 + t2];
            partial[(size_t)(row0 + tid) * 8 + by] = s;
        }
    } else {
#pragma unroll
        for (int i = 0; i < 4; ++i) {
            const int r = row0 + tm * 4 + i;
            float out[4];
#pragma unroll
            for (int j = 0; j < 4; ++j) {
                const int ccol = col0 + tn * 4 + j;
                float val = acc[i][j] + (bias ? bias[ccol] : 0.f);
                if (EPI == 1) {
                    val = 1.f / (1.f + expf(-val));
                } else if (EPI == 2) {
                    const float ph = tanhf(val);
                    const float zz = Ez[(size_t)r * H + ccol];
                    const float sh = Esh[(size_t)r * H + ccol];
                    val = (1.f - zz) * sh + zz * ph;
                } else if (EPI == 3) {
                    val = fmaxf(val, 0.f);
                }
                out[j] = val;
            }
            *(float4*)&C[(size_t)r * ldc + col0 + tn * 4] = *(float4*)out;
        }
    }
}

constexpr size_t SM_GEMM = (size_t)(2 * 32 * 68) * 4;              // 17408 B
constexpr size_t SM_STOP = (size_t)(2 * 32 * 68 + 64 * 17) * 4;    // 21760 B

template<int ASRC, int NSEG, int EPI>
__global__ __launch_bounds__(256)
void gemm_g(const float* __restrict__ A1, const float* __restrict__ A2, int lda,
            const float* __restrict__ W, const float* __restrict__ bias,
            float* __restrict__ C, int ldc,
            const int* __restrict__ gidx, int gt, const float* __restrict__ table,
            const float* __restrict__ node_rep, const int* __restrict__ cliq,
            const float* __restrict__ o_all,
            const int* __restrict__ rci, const int* __restrict__ rni,
            const float* __restrict__ Ez, const float* __restrict__ Esh,
            const float* __restrict__ Usw, float* __restrict__ partial)
{
    extern __shared__ float smem[];
    gemm_core<ASRC, NSEG, EPI>(smem, blockIdx.x, blockIdx.y, A1, A2, lda, W, bias,
                               C, ldc, gidx, gt, table, node_rep, cliq, o_all,
                               rci, rni, Ez, Esh, Usw, partial);
}

// Fused per-step dispatch: blocks [0,64) do the gathered hU GEMM (M=4096),
// blocks [64,72) do the z GEMM (M=512, K=1024, sigmoid).
__global__ __launch_bounds__(256)
void step1_kernel(const int* __restrict__ nei_h, int t, const float* __restrict__ table,
                  const float* __restrict__ Urw, float* __restrict__ hU,
                  const float* __restrict__ xs, const float* __restrict__ Wzw,
                  const float* __restrict__ Wzb, float* __restrict__ zb)
{
    extern __shared__ float smem[];
    if (blockIdx.x < 64) {
        gemm_core<1, 1, 0>(smem, blockIdx.x, blockIdx.y, nullptr, nullptr, 0,
                           Urw, nullptr, hU, H, nei_h, t, table,
                           nullptr, nullptr, nullptr, nullptr, nullptr,
                           nullptr, nullptr, nullptr, nullptr);
    } else {
        gemm_core<0, 2, 1>(smem, blockIdx.x - 64, blockIdx.y, xs, xs + H, 2 * H,
                           Wzw, Wzb, zb, H, nullptr, 0, nullptr,
                           nullptr, nullptr, nullptr, nullptr, nullptr,
                           nullptr, nullptr, nullptr, nullptr);
    }
}

// ---------------------------------------------------------------------------
// Per-step gathers: x (clique sum), sum_h, o.
// ---------------------------------------------------------------------------
__global__ __launch_bounds__(256)
void pre2_kernel(const float* __restrict__ node_rep, const int* __restrict__ clique_idx,
                 const int* __restrict__ nei_h, const int* __restrict__ nei_o,
                 const float* __restrict__ table,
                 float* __restrict__ xs, float* __restrict__ hs, float* __restrict__ ss,
                 float* __restrict__ sumh, float* __restrict__ oDst, int oStride, int t)
{
    const int i = blockIdx.x * 256 + threadIdx.x;   // B*H
    const int b = i >> 9, h = i & 511;
    const int* ci = clique_idx + ((size_t)b * T + t) * KC;
    float x = 0.f;
#pragma unroll
    for (int k = 0; k < KC; ++k)
        x += node_rep[((size_t)b * N_AT + ci[k]) * H + h];
    const int* hi = nei_h + ((size_t)b * T + t) * NB;
    const int* oi = nei_o + ((size_t)b * T + t) * NB;
    float sh = 0.f, so = 0.f;
#pragma unroll
    for (int n = 0; n < NB; ++n) {
        sh += table[(size_t)hi[n] * H + h];
        so += table[(size_t)oi[n] * H + h];
    }
    xs[(size_t)b * 1024 + h]       = x;
    xs[(size_t)b * 1024 + 512 + h] = sh;
    hs[(size_t)b * 1024 + h]       = x;
    ss[(size_t)b * 1024 + h]       = x;
    sumh[i] = sh;
    oDst[(size_t)b * oStride + h] = so;
}

// sum_g -> hs[:, H:]
__global__ __launch_bounds__(256)
void rsum2_kernel(const float* __restrict__ xrP, int xrStride,
                  const float* __restrict__ hU, const float* __restrict__ table,
                  const int* __restrict__ nei_h, float* __restrict__ hs, int t)
{
    const int i = blockIdx.x * 256 + threadIdx.x;
    const int b = i >> 9, h = i & 511;
    const int* hi = nei_h + ((size_t)b * T + t) * NB;
    const float xrv = xrP[(size_t)b * xrStride + h];
    float s = 0.f;
#pragma unroll
    for (int n = 0; n < NB; ++n) {
        const float hu = hU[((size_t)b * NB + n) * H + h];
        const float r  = 1.f / (1.f + expf(-(xrv + hu)));
        s += r * table[(size_t)hi[n] * H + h];
    }
    hs[(size_t)b * 1024 + 512 + h] = s;
}

// Root features into ss = [root_x | root_o]   (tier-B fallback)
__global__ __launch_bounds__(256)
void rootpre_kernel(const float* __restrict__ node_rep, const int* __restrict__ rci,
                    const int* __restrict__ rni, const float* __restrict__ table,
                    float* __restrict__ ss)
{
    const int i = blockIdx.x * 256 + threadIdx.x;
    const int b = i >> 9, h = i & 511;
    float x = 0.f;
#pragma unroll
    for (int k = 0; k < KC; ++k)
        x += node_rep[((size_t)b * N_AT + rci[b * KC + k]) * H + h];
    float so = 0.f;
#pragma unroll
    for (int n = 0; n < NB; ++n)
        so += table[(size_t)rni[b * NB + n] * H + h];
    ss[(size_t)b * 1024 + h]       = x;
    ss[(size_t)b * 1024 + 512 + h] = so;
}

__global__ __launch_bounds__(64)
void stopdot_kernel(const float* __restrict__ s1, const float* __restrict__ Usw,
                    const float* __restrict__ Usb,
                    float* __restrict__ out, int outStride, int outBase)
{
    const int b = blockIdx.x;
    const int lane = threadIdx.x;
    const float* row = s1 + (size_t)b * H;
    float s = 0.f;
    for (int h = lane; h < H; h += 64) s += row[h] * Usw[h];
#pragma unroll
    for (int off = 32; off; off >>= 1) s += __shfl_down(s, off);
    if (lane == 0) out[outBase + b * outStride] = s + Usb[0];
}

__global__ __launch_bounds__(256)
void stoploss_kernel(const float* __restrict__ scores, const int* __restrict__ direction,
                     float* __restrict__ accum)
{
    const int i = blockIdx.x * 256 + threadIdx.x;
    float loss = 0.f, acc = 0.f;
    if (i < BT + B) {
        const float s   = scores[i];
        const float tgt = (i < BT) ? (float)direction[i] : 0.f;
        loss = fmaxf(s, 0.f) - s * tgt + log1pf(expf(-fabsf(s)));
        const float p = (s >= 0.f) ? 1.f : 0.f;
        acc = (p == tgt) ? 1.f : 0.f;
    }
#pragma unroll
    for (int off = 32; off; off >>= 1) {
        loss += __shfl_down(loss, off);
        acc  += __shfl_down(acc, off);
    }
    if ((threadIdx.x & 63) == 0) {
        atomicAdd(&accum[3], loss);
        atomicAdd(&accum[4], acc);
    }
}

// tier-A: scores from partial dots; BCE loss + acc fused
__global__ __launch_bounds__(256)
void stopfin_kernel(const float* __restrict__ partial, const float* __restrict__ Usb,
                    const int* __restrict__ direction, float* __restrict__ accum)
{
    const int i = blockIdx.x * 256 + threadIdx.x;   // BT+B = 33280 exactly
    float loss = 0.f, acc = 0.f;
    {
        float s = Usb[0];
#pragma unroll
        for (int cb = 0; cb < 8; ++cb) s += partial[(size_t)i * 8 + cb];
        const float tgt = (i < BT) ? (float)direction[i] : 0.f;
        loss = fmaxf(s, 0.f) - s * tgt + log1pf(expf(-fabsf(s)));
        const float p = (s >= 0.f) ? 1.f : 0.f;
        acc = (p == tgt) ? 1.f : 0.f;
    }
#pragma unroll
    for (int off = 32; off; off >>= 1) {
        loss += __shfl_down(loss, off);
        acc  += __shfl_down(acc, off);
    }
    if ((threadIdx.x & 63) == 0) {
        atomicAdd(&accum[3], loss);
        atomicAdd(&accum[4], acc);
    }
}

// ---------------------------------------------------------------------------
// tier-A pred head phase 2: scores = s1 @ W_o + b, fused log-softmax CE + argmax.
// 32 rows/block, col-tiles of 64 (13 tiles cover V=780).
// ---------------------------------------------------------------------------
__global__ __launch_bounds__(256)
void ce_kernel(const float* __restrict__ s1_all, const float* __restrict__ Wo,
               const float* __restrict__ Wob, const int* __restrict__ direction,
               const int* __restrict__ ptgt, float* __restrict__ accum)
{
    __shared__ float s1T[512 * 34];   // transposed: s1T[k][r]
    __shared__ float Ws[32 * 68];
    __shared__ float blk[3];
    const int tid  = threadIdx.x;
    const int row0 = blockIdx.x * 32;

    for (int idx = tid; idx < 32 * 512; idx += 256) {
        const int r = idx >> 9, k = idx & 511;
        s1T[(size_t)k * 34 + r] = s1_all[(size_t)(row0 + r) * H + k];
    }
    if (tid < 3) blk[tid] = 0.f;
    __syncthreads();

    const int tm = tid >> 4, tn = tid & 15;   // rows tm*2..+1, cols tn*4..+3
    const int tgt0 = ptgt[row0 + tm * 2];
    const int tgt1 = ptgt[row0 + tm * 2 + 1];
    float m0 = -1e30f, m1 = -1e30f, ss0 = 0.f, ss1 = 0.f, st0 = 0.f, st1 = 0.f;
    float bv0 = -1e30f, bv1 = -1e30f;
    int   bj0 = 0, bj1 = 0;

    for (int ct = 0; ct < 13; ++ct) {
        const int col0 = ct * 64;
        float acc[2][4] = {};
        for (int k0 = 0; k0 < 512; k0 += 32) {
#pragma unroll
            for (int it = 0; it < 8; ++it) {
                const int idx = tid + it * 256;
                const int kk = idx >> 6, cc = idx & 63;
                const int col = col0 + cc;
                Ws[(size_t)kk * 68 + cc] = (col < V) ? Wo[(size_t)(k0 + kk) * V + col] : 0.f;
            }
            __syncthreads();
#pragma unroll
            for (int kk = 0; kk < 32; ++kk) {
                const float a0 = s1T[(size_t)(k0 + kk) * 34 + tm * 2];
                const float a1 = s1T[(size_t)(k0 + kk) * 34 + tm * 2 + 1];
                float w[4];
                *(float4*)w = *(const float4*)&Ws[kk * 68 + tn * 4];
#pragma unroll
                for (int j = 0; j < 4; ++j) {
                    acc[0][j] = fmaf(a0, w[j], acc[0][j]);
                    acc[1][j] = fmaf(a1, w[j], acc[1][j]);
                }
            }
            __syncthreads();
        }
#pragma unroll
        for (int j = 0; j < 4; ++j) {
            const int col = col0 + tn * 4 + j;
            if (col < V) {
                const float wb  = Wob[col];
                const float sc0 = acc[0][j] + wb;
                const float sc1 = acc[1][j] + wb;
                if (sc0 > m0) { ss0 = ss0 * expf(m0 - sc0) + 1.f; m0 = sc0; }
                else          { ss0 += expf(sc0 - m0); }
                if (sc1 > m1) { ss1 = ss1 * expf(m1 - sc1) + 1.f; m1 = sc1; }
                else          { ss1 += expf(sc1 - m1); }
                if (sc0 > bv0) { bv0 = sc0; bj0 = col; }
                if (sc1 > bv1) { bv1 = sc1; bj1 = col; }
                if (col == tgt0) st0 = sc0;
                if (col == tgt1) st1 = sc1;
            }
        }
    }

    // reduce across the 16 tn lanes (lane groups aligned within a wave)
#pragma unroll
    for (int off = 1; off < 16; off <<= 1) {
        float om, os;
        om = __shfl_xor(m0, off); os = __shfl_xor(ss0, off);
        { const float nm = fmaxf(m0, om); ss0 = ss0 * expf(m0 - nm) + os * expf(om - nm); m0 = nm; }
        om = __shfl_xor(m1, off); os = __shfl_xor(ss1, off);
        { const float nm = fmaxf(m1, om); ss1 = ss1 * expf(m1 - nm) + os * expf(om - nm); m1 = nm; }
        float obv; int obj;
        obv = __shfl_xor(bv0, off); obj = __shfl_xor(bj0, off);
        if (obv > bv0 || (obv == bv0 && obj < bj0)) { bv0 = obv; bj0 = obj; }
        obv = __shfl_xor(bv1, off); obj = __shfl_xor(bj1, off);
        if (obv > bv1 || (obv == bv1 && obj < bj1)) { bv1 = obv; bj1 = obj; }
        st0 += __shfl_xor(st0, off);
        st1 += __shfl_xor(st1, off);
    }
    if (tn == 0) {
        float ce_s = 0.f, cnt = 0.f, corr = 0.f;
        {
            const int row = row0 + tm * 2;
            if (direction[row] == 1) {
                ce_s += (m0 + logf(ss0)) - st0; cnt += 1.f;
                corr += (bj0 == tgt0) ? 1.f : 0.f;
            }
        }
        {
            const int row = row0 + tm * 2 + 1;
            if (direction[row] == 1) {
                ce_s += (m1 + logf(ss1)) - st1; cnt += 1.f;
                corr += (bj1 == tgt1) ? 1.f : 0.f;
            }
        }
        atomicAdd(&blk[0], ce_s); atomicAdd(&blk[1], cnt); atomicAdd(&blk[2], corr);
    }
    __syncthreads();
    if (tid == 0) {
        atomicAdd(&accum[0], blk[0]);
        atomicAdd(&accum[1], blk[1]);
        atomicAdd(&accum[2], blk[2]);
    }
}

// tier-B fallback fused pred head (round-0, verified)
constexpr int PH_ROWS = 8;
__global__ __launch_bounds__(256)
void predhead_kernel(const float* __restrict__ table,
                     const float* __restrict__ Ww, const float* __restrict__ Wb,
                     const float* __restrict__ Wo, const float* __restrict__ Wob,
                     const int* __restrict__ direction, const int* __restrict__ ptgt,
                     float* __restrict__ accum)
{
    __shared__ float hs[PH_ROWS][520];
    __shared__ float s1s[PH_ROWS][520];
    const int row0 = blockIdx.x * PH_ROWS;
    const int tid  = threadIdx.x;
    for (int i = tid; i < PH_ROWS * H; i += 256) {
        const int r = i >> 9, c = i & 511;
        hs[r][c] = table[(size_t)(row0 + r + 1) * H + c];
    }
    __syncthreads();
    const int r  = tid >> 5;
    const int tx = tid & 31;
    for (int j = 0; j < 16; ++j) {
        const int c = tx + j * 32;
        float acc = Wb[c];
        for (int k = 0; k < H; ++k) acc += hs[r][k] * Ww[(size_t)k * H + c];
        s1s[r][c] = fmaxf(acc, 0.f);
    }
    __syncthreads();
    const int row = row0 + r;
    const int tgt = ptgt[row];
    float m = -1e30f, ssum = 0.f, stgt = 0.f;
    float bestv = -1e30f; int bestj = 0;
    for (int v = tx; v < V; v += 32) {
        float sc = Wob[v];
        const float* wcol = Wo + v;
        for (int k = 0; k < H; ++k) sc += s1s[r][k] * wcol[(size_t)k * V];
        if (sc > m) { ssum = ssum * expf(m - sc) + 1.f; m = sc; }
        else        { ssum += expf(sc - m); }
        if (sc > bestv) { bestv = sc; bestj = v; }
        if (v == tgt) stgt = sc;
    }
#pragma unroll
    for (int off = 1; off < 32; off <<= 1) {
        const float om = __shfl_xor(m, off);
        const float os = __shfl_xor(ssum, off);
        const float nm = fmaxf(m, om);
        ssum = ssum * expf(m - nm) + os * expf(om - nm);
        m = nm;
        const float obv = __shfl_xor(bestv, off);
        const int   obj = __shfl_xor(bestj, off);
        if (obv > bestv || (obv == bestv && obj < bestj)) { bestv = obv; bestj = obj; }
        stgt += __shfl_xor(stgt, off);
    }
    if (tx == 0) {
        const float ce   = (m + logf(ssum)) - stgt;
        const float mask = (direction[row] == 1) ? 1.f : 0.f;
        const float corr = (bestj == tgt) ? 1.f : 0.f;
        atomicAdd(&accum[0], ce * mask);
        atomicAdd(&accum[1], mask);
        atomicAdd(&accum[2], corr * mask);
    }
}

__global__ void finalize_kernel(const float* __restrict__ accum, float* __restrict__ out)
{
    if (threadIdx.x == 0) {
        out[0] = accum[0] / (float)B;
        out[1] = accum[3] / (float)B;
        out[2] = accum[2] / accum[1];
        out[3] = accum[4] / (float)(BT + B);
    }
}

// ---------------------------------------------------------------------------
extern "C" void kernel_launch(void* const* d_in, const int* in_sizes, int n_in,
                              void* d_out, int out_size, void* d_ws, size_t ws_size,
                              hipStream_t stream)
{
    (void)in_sizes; (void)n_in; (void)out_size;

    const float* node_rep        = (const float*)d_in[0];
    const int*   clique_idx      = (const int*)d_in[1];
    const int*   root_clique_idx = (const int*)d_in[2];
    const int*   nei_h_idx       = (const int*)d_in[3];
    const int*   nei_o_idx       = (const int*)d_in[4];
    const int*   root_nei_idx    = (const int*)d_in[5];
    const int*   direction       = (const int*)d_in[6];
    const int*   pred_target     = (const int*)d_in[7];
    const float* W_z_w = (const float*)d_in[8];
    const float* W_z_b = (const float*)d_in[9];
    const float* W_r_w = (const float*)d_in[10];
    const float* W_r_b = (const float*)d_in[11];
    const float* U_r_w = (const float*)d_in[12];
    const float* W_h_w = (const float*)d_in[13];
    const float* W_h_b = (const float*)d_in[14];
    const float* W_w   = (const float*)d_in[15];
    const float* W_b   = (const float*)d_in[16];
    const float* U_w   = (const float*)d_in[17];
    const float* U_b   = (const float*)d_in[18];
    const float* W_o_w = (const float*)d_in[19];
    const float* W_o_b = (const float*)d_in[20];
    const float* U_s_w = (const float*)d_in[21];
    const float* U_s_b = (const float*)d_in[22];

    float* ws = (float*)d_ws;
    size_t off = 0;
    auto alloc = [&](size_t n) { float* p = ws + off; off += n; return p; };

    float* table  = alloc((size_t)NMSG * H);
    float* hU     = alloc((size_t)B * NB * H);
    float* xs     = alloc((size_t)B * 2 * H);
    float* hs     = alloc((size_t)B * 2 * H);
    float* ss     = alloc((size_t)B * 2 * H);
    float* sumh   = alloc((size_t)B * H);
    float* zb     = alloc((size_t)B * H);
    float* xr     = alloc((size_t)B * H);
    float* stop_scores = alloc(BT + B);
    float* accum  = alloc(8);

    const size_t availF = ws_size / sizeof(float);
    float *s1_all = nullptr, *o_all = nullptr, *partial = nullptr, *xr_all = nullptr;
    if (off + (size_t)BT * H <= availF)                 s1_all = alloc((size_t)BT * H);
    if (off + (size_t)BT * H + (size_t)(BT + B) * 8 <= availF) {
        o_all   = alloc((size_t)BT * H);
        partial = alloc((size_t)(BT + B) * 8);
    }
    if (off + (size_t)BT * H <= availF)                 xr_all = alloc((size_t)BT * H);

    hipMemsetAsync(table, 0, (size_t)NMSG * H * sizeof(float), stream);
    hipMemsetAsync(accum, 0, 8 * sizeof(float), stream);

    const int  BH_blocks = (B * H) / 256;   // 1024
    const dim3 gSmall(8, 8);                // M=512 GEMMs
    const dim3 gStep(72, 8);                // fused hU (64) + z (8)

    // xr_all = x_all @ W_r + b_r  (clique-gathered A), once
    if (xr_all) {
        gemm_g<2, 1, 0><<<dim3(BT / 64, 8), 256, SM_GEMM, stream>>>(
            nullptr, nullptr, 0, W_r_w, W_r_b, xr_all, H,
            nullptr, 0, nullptr, node_rep, clique_idx,
            nullptr, nullptr, nullptr, nullptr, nullptr, nullptr, nullptr);
    }

    for (int t = 0; t < T; ++t) {
        float* oDst    = o_all ? (o_all + (size_t)t * H) : (ss + H);
        const int oStr = o_all ? (T * H) : (2 * H);
        pre2_kernel<<<BH_blocks, 256, 0, stream>>>(node_rep, clique_idx, nei_h_idx,
                                                   nei_o_idx, table, xs, hs, ss,
                                                   sumh, oDst, oStr, t);
        // fused: hU = gather(table) @ U_r   ||   z = sigmoid([x|sum_h] @ W_z + b)
        step1_kernel<<<gStep, 256, SM_GEMM, stream>>>(nei_h_idx, t, table, U_r_w, hU,
                                                      xs, W_z_w, W_z_b, zb);
        if (!xr_all) {
            gemm_g<0, 1, 0><<<gSmall, 256, SM_GEMM, stream>>>(
                xs, nullptr, 2 * H, W_r_w, W_r_b, xr, H,
                nullptr, 0, nullptr, nullptr, nullptr,
                nullptr, nullptr, nullptr, nullptr, nullptr, nullptr, nullptr);
        }
        const float* xrP   = xr_all ? (xr_all + (size_t)t * H) : xr;
        const int    xrStr = xr_all ? (T * H) : H;
        rsum2_kernel<<<BH_blocks, 256, 0, stream>>>(xrP, xrStr, hU, table,
                                                    nei_h_idx, hs, t);
        // new_h = (1-z)*sum_h + z*tanh([x|sum_g] @ W_h + b)  -> table rows b*T+t+1
        gemm_g<0, 2, 2><<<gSmall, 256, SM_GEMM, stream>>>(
            hs, hs + H, 2 * H, W_h_w, W_h_b, table + (size_t)(t + 1) * H, T * H,
            nullptr, 0, nullptr, nullptr, nullptr,
            nullptr, nullptr, nullptr, zb, sumh, nullptr, nullptr);
        if (!o_all) {
            // in-loop stop head: s1 = relu([x|o] @ U_w + U_b); score dot
            gemm_g<0, 2, 3><<<gSmall, 256, SM_GEMM, stream>>>(
                ss, ss + H, 2 * H, U_w, U_b, zb, H,
                nullptr, 0, nullptr, nullptr, nullptr,
                nullptr, nullptr, nullptr, nullptr, nullptr, nullptr, nullptr);
            stopdot_kernel<<<B, 64, 0, stream>>>(zb, U_s_w, U_s_b, stop_scores, T, t);
        }
    }

    if (o_all) {
        // deferred stop head over all BT + B rows (root rows gathered in-kernel)
        gemm_g<3, 2, 4><<<dim3((BT + B) / 64, 8), 256, SM_STOP, stream>>>(
            nullptr, nullptr, 0, U_w, U_b, nullptr, 0,
            nullptr, 0, table, node_rep, clique_idx,
            o_all, root_clique_idx, root_nei_idx, nullptr, nullptr, U_s_w, partial);
        stopfin_kernel<<<(BT + B) / 256, 256, 0, stream>>>(partial, U_s_b, direction, accum);
    } else {
        rootpre_kernel<<<BH_blocks, 256, 0, stream>>>(node_rep, root_clique_idx,
                                                      root_nei_idx, table, ss);
        gemm_g<0, 2, 3><<<gSmall, 256, SM_GEMM, stream>>>(
            ss, ss + H, 2 * H, U_w, U_b, zb, H,
            nullptr, 0, nullptr, nullptr, nullptr,
            nullptr, nullptr, nullptr, nullptr, nullptr, nullptr, nullptr);
        stopdot_kernel<<<B, 64, 0, stream>>>(zb, U_s_w, U_s_b, stop_scores, 1, BT);
        stoploss_kernel<<<(BT + B + 255) / 256, 256, 0, stream>>>(stop_scores, direction, accum);
    }

    if (s1_all) {
        // pred head: s1_all = relu(h_all @ W_w + W_b); h_all = table rows 1..BT
        gemm_g<0, 1, 3><<<dim3(BT / 64, 8), 256, SM_GEMM, stream>>>(
            table + H, nullptr, H, W_w, W_b, s1_all, H,
            nullptr, 0, nullptr, nullptr, nullptr,
            nullptr, nullptr, nullptr, nullptr, nullptr, nullptr, nullptr);
        ce_kernel<<<BT / 32, 256, 0, stream>>>(s1_all, W_o_w, W_o_b,
                                               direction, pred_target, accum);
    } else {
        predhead_kernel<<<BT / PH_ROWS, 256, 0, stream>>>(table, W_w, W_b, W_o_w, W_o_b,
                                                          direction, pred_target, accum);
    }

    finalize_kernel<<<1, 64, 0, stream>>>(accum, (float*)d_out);
}